// Round 19
// baseline (356.311 us; speedup 1.0000x reference)
//
#include <hip/hip_runtime.h>
#include <hip/hip_bf16.h>

#define DDIM 128
#define RDIM 32
#define PBLK 256
#define BLK  256      // 4 waves
#define HSTR 40       // hs row stride u16 (80B -> 2-way max aliasing, proven)

typedef __attribute__((ext_vector_type(8))) short bf16x8;
typedef __attribute__((ext_vector_type(4))) float f32x4;

__device__ __forceinline__ float tanh_fast(float v) {
  float e = __expf(2.f * v);
  return 1.f - 2.f * __builtin_amdgcn_rcpf(e + 1.f);
}
__device__ __forceinline__ float sigmoid_fast(float v) {
  return __builtin_amdgcn_rcpf(1.f + __expf(-v));
}
__device__ __forceinline__ unsigned short f2bf(float f) {  // RNE f32->bf16
  unsigned u = __float_as_uint(f);
  u += 0x7fffu + ((u >> 16) & 1u);
  return (unsigned short)(u >> 16);
}
__device__ __forceinline__ float bf2f(unsigned short s) {
  return __uint_as_float(((unsigned)s) << 16);
}
__device__ __forceinline__ unsigned pkbf(float lo, float hi) {
  __hip_bfloat162 t2 = __float22bfloat162_rn(make_float2(lo, hi));
  return *reinterpret_cast<unsigned*>(&t2);
}
__device__ __forceinline__ int lower_bound(const int* __restrict__ b, int n, int v) {
  int lo = 0, hi = n;
  while (lo < hi) { int m = (lo + hi) >> 1; if (b[m] < v) lo = m + 1; else hi = m; }
  return lo;
}

// ---------------------------------------------------------------------------
// K0: bf16 A-fragments of W1^T / W2^T. A-frag: row=l&15, k=(l>>4)*8+j.
// ---------------------------------------------------------------------------
__global__ void k0_prep(const float* __restrict__ w1, const float* __restrict__ w2,
                        unsigned short* __restrict__ w1tf, unsigned short* __restrict__ w2tf)
{
  const int i  = blockIdx.x * blockDim.x + threadIdx.x;   // 0..1023
  const int l  = i & 63;
  const int lr = l & 15, q = l >> 4;
  if (i < 512) {
    const int frag = i >> 6;             // mt2*4+kk
    const int mt2 = frag >> 2, kk = frag & 3;
    bf16x8 v;
    #pragma unroll
    for (int j = 0; j < 8; ++j)
      v[j] = (short)f2bf(w1[(size_t)(kk * 32 + q * 8 + j) * RDIM + mt2 * 16 + lr]);
    *(bf16x8*)&w1tf[(size_t)i * 8] = v;
  } else {
    const int mt = (i - 512) >> 6;
    bf16x8 v;
    #pragma unroll
    for (int j = 0; j < 8; ++j)
      v[j] = (short)f2bf(w2[(size_t)(q * 8 + j) * DDIM + mt * 16 + lr]);
    *(bf16x8*)&w2tf[(size_t)(i - 512) * 8] = v;
  }
}

__global__ void kb_bounds(const int* __restrict__ batch, int* __restrict__ bounds,
                          int N, int G)
{
  const int g = blockIdx.x * blockDim.x + threadIdx.x;
  if (g <= G) bounds[g] = lower_bound(batch, N, g);
}

// ---------------------------------------------------------------------------
// K_FUSED v7: R17 (best) + register double-buffered tile state.
// While computing tile t from registers, the ds_reads for tile t+1 issue into
// the alternate named register set -> LDS-read latency hides under compute.
// 2-slot DMA ring per wave unchanged (counted vmcnt(8)). b2/tg in LDS
// (broadcast reads) to fund the extra 64 VGPRs of the doubled state.
// ---------------------------------------------------------------------------
__global__ __launch_bounds__(BLK, 2) void k_fused(
    const float* __restrict__ x,
    const unsigned short* __restrict__ w1tf, const float* __restrict__ b1,
    const unsigned short* __restrict__ w2tf, const float* __restrict__ b2,
    const float* __restrict__ W, const int* __restrict__ bounds,
    float* __restrict__ out, int N)
{
  __shared__ float ring[4][2][2048];             // 65,536 B
  __shared__ unsigned short hs4[4][16 * HSTR];   //  5,120 B
  __shared__ float part[4][132];                 //  2,112 B
  __shared__ float meanv[DDIM];                  //    512 B
  __shared__ float tgs[DDIM];                    //    512 B
  __shared__ float b2s[DDIM];                    //    512 B  (74,304 total)

  const int t  = threadIdx.x;
  const int l  = t & 63;
  const int w  = t >> 6;
  const int lr = l & 15;
  const int q  = l >> 4;
  const int g  = blockIdx.x;
  const int lo = bounds[g], hi = bounds[g + 1];
  const int cnt = hi - lo;
  unsigned short* hs = hs4[w];

  if (cnt <= 0) { if (t < DDIM) out[(size_t)g * DDIM + t] = 0.f; return; }

  // ---- weight A-frags in registers (L2-hot 16B loads), ONCE ----
  bf16x8 w1r[2][4], w2r[8];
  #pragma unroll
  for (int mt2 = 0; mt2 < 2; ++mt2)
    #pragma unroll
    for (int kk = 0; kk < 4; ++kk)
      w1r[mt2][kk] = *(const bf16x8*)&w1tf[(size_t)((mt2 * 4 + kk) * 64 + l) * 8];
  #pragma unroll
  for (int mt = 0; mt < 8; ++mt)
    w2r[mt] = *(const bf16x8*)&w2tf[(size_t)(mt * 64 + l) * 8];

  const float4 b1q0 = *(const float4*)(b1 + q * 4);
  const float4 b1q1 = *(const float4*)(b1 + 16 + q * 4);
  if (t < DDIM) b2s[t] = b2[t];
  __syncthreads();

  const int sr  = l >> 5;        // stage row parity
  const int sc  = l & 31;        // stage 16B-chunk col
  const int swz = lr & 7;
  const int ntile = (cnt + 15) >> 4;

  // ---- async fill of slot s with tile starting at row tb ----
  auto fill = [&](int s, int tb) {
    float* lds = ring[w][s];
    #pragma unroll
    for (int j = 0; j < 8; ++j) {
      const int r   = j * 2 + sr;
      const int row = lo + min(tb + r, cnt - 1);
      const int lc  = sc ^ (r & 7);
      __builtin_amdgcn_global_load_lds(x + (size_t)row * DDIM + lc * 4,
                                       lds + j * 256, 16, 0, 0);
    }
  };

  // ---- slot s -> named registers (bf16 xf frags + packed gate xg) ----
  auto loadregs = [&](int s, bf16x8 (&xf)[4], uint2 (&xg)[8]) {
    float* lds = ring[w][s];
    #pragma unroll
    for (int kk = 0; kk < 4; ++kk) {
      const int c0 = kk * 8 + q * 2;
      float4 a = *(const float4*)&lds[lr * 128 + ((c0    ) ^ swz) * 4];
      float4 b = *(const float4*)&lds[lr * 128 + ((c0 + 1) ^ swz) * 4];
      uint4 u;
      u.x = pkbf(a.x, a.y); u.y = pkbf(a.z, a.w);
      u.z = pkbf(b.x, b.y); u.w = pkbf(b.z, b.w);
      xf[kk] = *(bf16x8*)&u;
    }
    #pragma unroll
    for (int mt = 0; mt < 8; ++mt) {
      float4 v = *(const float4*)&lds[lr * 128 + ((mt * 4 + q) ^ swz) * 4];
      xg[mt].x = pkbf(v.x, v.y); xg[mt].y = pkbf(v.z, v.w);
    }
  };

  // ---- MLP + gate from registers; cacc ends as gated y (f32) ----
  auto compute = [&](const bf16x8 (&xf)[4], const uint2 (&xg)[8],
                     f32x4 (&cacc)[8]) {
    f32x4 hacc[2];
    hacc[0][0] = b1q0.x; hacc[0][1] = b1q0.y; hacc[0][2] = b1q0.z; hacc[0][3] = b1q0.w;
    hacc[1][0] = b1q1.x; hacc[1][1] = b1q1.y; hacc[1][2] = b1q1.z; hacc[1][3] = b1q1.w;
    #pragma unroll
    for (int kk = 0; kk < 4; ++kk) {
      hacc[0] = __builtin_amdgcn_mfma_f32_16x16x32_bf16(w1r[0][kk], xf[kk], hacc[0], 0, 0, 0);
      hacc[1] = __builtin_amdgcn_mfma_f32_16x16x32_bf16(w1r[1][kk], xf[kk], hacc[1], 0, 0, 0);
    }
    #pragma unroll
    for (int mt2 = 0; mt2 < 2; ++mt2) {
      float h0 = fmaxf(hacc[mt2][0], 0.f), h1 = fmaxf(hacc[mt2][1], 0.f);
      float h2 = fmaxf(hacc[mt2][2], 0.f), h3 = fmaxf(hacc[mt2][3], 0.f);
      uint2 p; p.x = pkbf(h0, h1); p.y = pkbf(h2, h3);
      *(uint2*)&hs[lr * HSTR + mt2 * 16 + q * 4] = p;
    }
    bf16x8 ah = *(const bf16x8*)&hs[lr * HSTR + q * 8];
    #pragma unroll
    for (int mt = 0; mt < 8; ++mt) {
      float4 bv = *(const float4*)&b2s[mt * 16 + q * 4];   // LDS broadcast
      cacc[mt][0] = bv.x; cacc[mt][1] = bv.y; cacc[mt][2] = bv.z; cacc[mt][3] = bv.w;
    }
    #pragma unroll
    for (int mt = 0; mt < 8; ++mt)
      cacc[mt] = __builtin_amdgcn_mfma_f32_16x16x32_bf16(w2r[mt], ah, cacc[mt], 0, 0, 0);
    #pragma unroll
    for (int mt = 0; mt < 8; ++mt) {
      float x0 = bf2f((unsigned short)(xg[mt].x & 0xffffu));
      float x1 = bf2f((unsigned short)(xg[mt].x >> 16));
      float x2 = bf2f((unsigned short)(xg[mt].y & 0xffffu));
      float x3 = bf2f((unsigned short)(xg[mt].y >> 16));
      cacc[mt][0] = x0 * (1.f + tanh_fast(cacc[mt][0]));
      cacc[mt][1] = x1 * (1.f + tanh_fast(cacc[mt][1]));
      cacc[mt][2] = x2 * (1.f + tanh_fast(cacc[mt][2]));
      cacc[mt][3] = x3 * (1.f + tanh_fast(cacc[mt][3]));
    }
  };

  // per-tile pipeline step: refill own slot (t+8), wait t+4, load next regs,
  // compute current from regs.  p = slot parity of tile ti.
  auto step = [&](int ti, int p,
                  const bf16x8 (&xfC)[4], const uint2 (&xgC)[8],
                  bf16x8 (&xfN)[4], uint2 (&xgN)[8], f32x4 (&cacc)[8]) {
    asm volatile("s_waitcnt lgkmcnt(0)" ::: "memory");   // C's slot reads retired
    if (ti + 8 < ntile) {
      fill(p, (ti + 8) * 16);
      asm volatile("s_waitcnt vmcnt(8)" ::: "memory");   // t+4's data landed
    } else if (ti + 4 < ntile) {
      asm volatile("s_waitcnt vmcnt(0)" ::: "memory");
    }
    if (ti + 4 < ntile) loadregs(p ^ 1, xfN, xgN);       // overlaps compute
    compute(xfC, xgC, cacc);
  };

  // ================= PASS 1: mean accumulate =================
  float macc[8][4];
  #pragma unroll
  for (int mt = 0; mt < 8; ++mt)
    #pragma unroll
    for (int c = 0; c < 4; ++c) macc[mt][c] = 0.f;

  {
    bf16x8 xfA[4], xfB[4]; uint2 xgA[8], xgB[8];
    int ti = w;
    if (ti < ntile) {
      fill(0, ti * 16);
      asm volatile("s_waitcnt vmcnt(0)" ::: "memory");
      loadregs(0, xfA, xgA);
      if (ti + 4 < ntile) fill(1, (ti + 4) * 16);
    }
    int p = 0;
    while (ti < ntile) {
      f32x4 cacc[8];
      if (p == 0) step(ti, 0, xfA, xgA, xfB, xgB, cacc);
      else        step(ti, 1, xfB, xgB, xfA, xgA, cacc);
      if (ti * 16 + lr < cnt) {
        #pragma unroll
        for (int mt = 0; mt < 8; ++mt)
          #pragma unroll
          for (int c = 0; c < 4; ++c) macc[mt][c] += cacc[mt][c];
      }
      ti += 4; p ^= 1;
    }
  }
  __syncthreads();

  // ---- mean reduce: lr lanes (xor 1,2,4,8), cross-wave via part ----
  #pragma unroll
  for (int mt = 0; mt < 8; ++mt)
    #pragma unroll
    for (int c = 0; c < 4; ++c) {
      float v = macc[mt][c];
      v += __shfl_xor(v, 1, 64);
      v += __shfl_xor(v, 2, 64);
      v += __shfl_xor(v, 4, 64);
      v += __shfl_xor(v, 8, 64);
      macc[mt][c] = v;
    }
  if (lr == 0) {
    #pragma unroll
    for (int mt = 0; mt < 8; ++mt)
      *(float4*)&part[w][mt * 16 + q * 4] =
          make_float4(macc[mt][0], macc[mt][1], macc[mt][2], macc[mt][3]);
  }
  __syncthreads();
  if (t < DDIM) {
    float m = part[0][t] + part[1][t] + part[2][t] + part[3][t];
    meanv[t] = m / (float)cnt;
  }
  __syncthreads();

  // ---- tg = tanh(mean @ W): 2 thr/col x 64 k, coalesced ----
  {
    const int c = t & 127, s = t >> 7;
    float a = 0.f;
    #pragma unroll 8
    for (int k = 0; k < 64; ++k)
      a = fmaf(meanv[s * 64 + k], W[(size_t)(s * 64 + k) * DDIM + c], a);
    part[s][c] = a;
  }
  __syncthreads();
  if (t < DDIM) tgs[t] = tanh_fast(part[0][t] + part[1][t]);
  __syncthreads();

  // ================= PASS 2: re-stream, coef, out =================
  float oacc[8][4];
  #pragma unroll
  for (int mt = 0; mt < 8; ++mt)
    #pragma unroll
    for (int c = 0; c < 4; ++c) oacc[mt][c] = 0.f;

  {
    bf16x8 xfA[4], xfB[4]; uint2 xgA[8], xgB[8];
    int ti = w;
    if (ti < ntile) {
      fill(0, ti * 16);
      asm volatile("s_waitcnt vmcnt(0)" ::: "memory");
      loadregs(0, xfA, xgA);
      if (ti + 4 < ntile) fill(1, (ti + 4) * 16);
    }
    int p = 0;
    while (ti < ntile) {
      f32x4 cacc[8];
      if (p == 0) step(ti, 0, xfA, xgA, xfB, xgB, cacc);
      else        step(ti, 1, xfB, xgB, xfA, xgA, cacc);
      float pp = 0.f;
      #pragma unroll
      for (int mt = 0; mt < 8; ++mt) {
        float4 tg4 = *(const float4*)&tgs[mt * 16 + q * 4];  // LDS broadcast
        pp = fmaf(cacc[mt][0], tg4.x, pp); pp = fmaf(cacc[mt][1], tg4.y, pp);
        pp = fmaf(cacc[mt][2], tg4.z, pp); pp = fmaf(cacc[mt][3], tg4.w, pp);
      }
      pp += __shfl_xor(pp, 16, 64);
      pp += __shfl_xor(pp, 32, 64);
      const float coef = sigmoid_fast(pp);
      if (ti * 16 + lr < cnt) {
        #pragma unroll
        for (int mt = 0; mt < 8; ++mt)
          #pragma unroll
          for (int c = 0; c < 4; ++c)
            oacc[mt][c] = fmaf(coef, cacc[mt][c], oacc[mt][c]);
      }
      ti += 4; p ^= 1;
    }
  }
  __syncthreads();

  // ---- out reduce ----
  #pragma unroll
  for (int mt = 0; mt < 8; ++mt)
    #pragma unroll
    for (int c = 0; c < 4; ++c) {
      float v = oacc[mt][c];
      v += __shfl_xor(v, 1, 64);
      v += __shfl_xor(v, 2, 64);
      v += __shfl_xor(v, 4, 64);
      v += __shfl_xor(v, 8, 64);
      oacc[mt][c] = v;
    }
  if (lr == 0) {
    #pragma unroll
    for (int mt = 0; mt < 8; ++mt)
      *(float4*)&part[w][mt * 16 + q * 4] =
          make_float4(oacc[mt][0], oacc[mt][1], oacc[mt][2], oacc[mt][3]);
  }
  __syncthreads();
  if (t < DDIM)
    out[(size_t)g * DDIM + t] = part[0][t] + part[1][t] + part[2][t] + part[3][t];
}

// ---------------------------------------------------------------------------
extern "C" void kernel_launch(void* const* d_in, const int* in_sizes, int n_in,
                              void* d_out, int out_size, void* d_ws, size_t ws_size,
                              hipStream_t stream) {
  const float* x     = (const float*)d_in[0];
  const int*   batch = (const int*)d_in[1];
  const float* w1 = (const float*)d_in[3];
  const float* b1 = (const float*)d_in[4];
  const float* w2 = (const float*)d_in[5];
  const float* b2 = (const float*)d_in[6];
  const float* W  = (const float*)d_in[7];
  float* out = (float*)d_out;

  const int N = in_sizes[0] / DDIM;
  const int G = out_size / DDIM;

  // ws: [w1tf 4096 u16][w2tf 4096 u16][bounds G+1 int]
  unsigned short* w1tf = (unsigned short*)d_ws;
  unsigned short* w2tf = w1tf + 4096;
  int* bounds = (int*)(w2tf + 4096);
  (void)ws_size; (void)n_in;

  hipLaunchKernelGGL(k0_prep, dim3(4), dim3(PBLK), 0, stream, w1, w2, w1tf, w2tf);
  hipLaunchKernelGGL(kb_bounds, dim3((G + 1 + PBLK - 1) / PBLK), dim3(PBLK), 0, stream,
                     batch, bounds, N, G);
  hipLaunchKernelGGL(k_fused, dim3(G), dim3(BLK), 0, stream,
                     x, w1tf, b1, w2tf, b2, W, bounds, out, N);
}

// Round 20
// 126.917 us; speedup vs baseline: 2.8074x; 2.8074x over previous
//
#include <hip/hip_runtime.h>
#include <hip/hip_bf16.h>

#define DDIM 128
#define RDIM 32
#define PBLK 256
#define BLK  256      // 4 waves
#define HSTR 40       // hs row stride u16

typedef __attribute__((ext_vector_type(8))) short bf16x8;
typedef __attribute__((ext_vector_type(4))) float f32x4;

__device__ __forceinline__ float tanh_fast(float v) {
  float e = __expf(2.f * v);
  return 1.f - 2.f * __builtin_amdgcn_rcpf(e + 1.f);
}
__device__ __forceinline__ float sigmoid_fast(float v) {
  return __builtin_amdgcn_rcpf(1.f + __expf(-v));
}
__device__ __forceinline__ unsigned short f2bf(float f) {  // RNE f32->bf16
  unsigned u = __float_as_uint(f);
  u += 0x7fffu + ((u >> 16) & 1u);
  return (unsigned short)(u >> 16);
}
__device__ __forceinline__ float bf2f(unsigned short s) {
  return __uint_as_float(((unsigned)s) << 16);
}
__device__ __forceinline__ unsigned pkbf(float lo, float hi) {
  __hip_bfloat162 t2 = __float22bfloat162_rn(make_float2(lo, hi));
  return *reinterpret_cast<unsigned*>(&t2);
}
__device__ __forceinline__ int lower_bound(const int* __restrict__ b, int n, int v) {
  int lo = 0, hi = n;
  while (lo < hi) { int m = (lo + hi) >> 1; if (b[m] < v) lo = m + 1; else hi = m; }
  return lo;
}

// ---------------------------------------------------------------------------
// K0: bf16 A-fragments of W1^T / W2^T. A-frag: row=l&15, k=(l>>4)*8+j.
// ---------------------------------------------------------------------------
__global__ void k0_prep(const float* __restrict__ w1, const float* __restrict__ w2,
                        unsigned short* __restrict__ w1tf, unsigned short* __restrict__ w2tf)
{
  const int i  = blockIdx.x * blockDim.x + threadIdx.x;   // 0..1023
  const int l  = i & 63;
  const int lr = l & 15, q = l >> 4;
  if (i < 512) {
    const int frag = i >> 6;             // mt2*4+kk
    const int mt2 = frag >> 2, kk = frag & 3;
    bf16x8 v;
    #pragma unroll
    for (int j = 0; j < 8; ++j)
      v[j] = (short)f2bf(w1[(size_t)(kk * 32 + q * 8 + j) * RDIM + mt2 * 16 + lr]);
    *(bf16x8*)&w1tf[(size_t)i * 8] = v;
  } else {
    const int mt = (i - 512) >> 6;
    bf16x8 v;
    #pragma unroll
    for (int j = 0; j < 8; ++j)
      v[j] = (short)f2bf(w2[(size_t)(q * 8 + j) * DDIM + mt * 16 + lr]);
    *(bf16x8*)&w2tf[(size_t)(i - 512) * 8] = v;
  }
}

__global__ void kb_bounds(const int* __restrict__ batch, int* __restrict__ bounds,
                          int N, int G)
{
  const int g = blockIdx.x * blockDim.x + threadIdx.x;
  if (g <= G) bounds[g] = lower_bound(batch, N, g);
}

// ---------------------------------------------------------------------------
// K_FUSED v5 (R17, best): fused per-graph, 2-slot DMA ring, all global
// constants hoisted out of the tile loops so the counted vmcnt(8) keeps the
// next slot's 8 DMA fills in flight across compute.
// ---------------------------------------------------------------------------
__global__ __launch_bounds__(BLK, 2) void k_fused(
    const float* __restrict__ x,
    const unsigned short* __restrict__ w1tf, const float* __restrict__ b1,
    const unsigned short* __restrict__ w2tf, const float* __restrict__ b2,
    const float* __restrict__ W, const int* __restrict__ bounds,
    float* __restrict__ out, int N)
{
  __shared__ float ring[4][2][2048];             // 65,536 B
  __shared__ unsigned short hs4[4][16 * HSTR];   //  5,120 B
  __shared__ float part[4][132];                 //  2,112 B
  __shared__ float meanv[DDIM];                  //    512 B
  __shared__ float tgs[DDIM];                    //    512 B  (73,792 total)

  const int t  = threadIdx.x;
  const int l  = t & 63;
  const int w  = t >> 6;
  const int lr = l & 15;
  const int q  = l >> 4;
  const int g  = blockIdx.x;
  const int lo = bounds[g], hi = bounds[g + 1];
  const int cnt = hi - lo;
  unsigned short* hs = hs4[w];

  if (cnt <= 0) { if (t < DDIM) out[(size_t)g * DDIM + t] = 0.f; return; }

  // ---- weight A-frags in registers (L2-hot 16B loads), ONCE ----
  bf16x8 w1r[2][4], w2r[8];
  #pragma unroll
  for (int mt2 = 0; mt2 < 2; ++mt2)
    #pragma unroll
    for (int kk = 0; kk < 4; ++kk)
      w1r[mt2][kk] = *(const bf16x8*)&w1tf[(size_t)((mt2 * 4 + kk) * 64 + l) * 8];
  #pragma unroll
  for (int mt = 0; mt < 8; ++mt)
    w2r[mt] = *(const bf16x8*)&w2tf[(size_t)(mt * 64 + l) * 8];

  // ---- biases in registers, ONCE (keeps tile loops VMEM-free) ----
  const float4 b1q0 = *(const float4*)(b1 + q * 4);
  const float4 b1q1 = *(const float4*)(b1 + 16 + q * 4);
  float4 b2v[8];
  #pragma unroll
  for (int mt = 0; mt < 8; ++mt)
    b2v[mt] = *(const float4*)(b2 + mt * 16 + q * 4);

  const int sr  = l >> 5;        // stage row parity
  const int sc  = l & 31;        // stage 16B-chunk col
  const int swz = lr & 7;
  const int ntile = (cnt + 15) >> 4;

  // ---- async fill: 8 x global_load_lds(16B), source pre-swizzled ----
  auto fill = [&](int s, int tb) {
    float* lds = ring[w][s];
    #pragma unroll
    for (int j = 0; j < 8; ++j) {
      const int r   = j * 2 + sr;
      const int row = lo + min(tb + r, cnt - 1);      // clamp inside graph
      const int lc  = sc ^ (r & 7);
      __builtin_amdgcn_global_load_lds(x + (size_t)row * DDIM + lc * 4,
                                       lds + j * 256, 16, 0, 0);
    }
  };

  // ---- MLP on one staged tile: y[mt][c] for node lr, d=mt*16+q*4+c ----
  auto mlp = [&](int s, float (&y)[8][4]) {
    float* lds = ring[w][s];
    bf16x8 xf[4];
    #pragma unroll
    for (int kk = 0; kk < 4; ++kk) {
      const int c0 = kk * 8 + q * 2;
      float4 a = *(const float4*)&lds[lr * 128 + ((c0    ) ^ swz) * 4];
      float4 b = *(const float4*)&lds[lr * 128 + ((c0 + 1) ^ swz) * 4];
      uint4 u;
      u.x = pkbf(a.x, a.y); u.y = pkbf(a.z, a.w);
      u.z = pkbf(b.x, b.y); u.w = pkbf(b.z, b.w);
      xf[kk] = *(bf16x8*)&u;
    }
    f32x4 hacc[2];
    hacc[0][0] = b1q0.x; hacc[0][1] = b1q0.y; hacc[0][2] = b1q0.z; hacc[0][3] = b1q0.w;
    hacc[1][0] = b1q1.x; hacc[1][1] = b1q1.y; hacc[1][2] = b1q1.z; hacc[1][3] = b1q1.w;
    #pragma unroll
    for (int kk = 0; kk < 4; ++kk) {
      hacc[0] = __builtin_amdgcn_mfma_f32_16x16x32_bf16(w1r[0][kk], xf[kk], hacc[0], 0, 0, 0);
      hacc[1] = __builtin_amdgcn_mfma_f32_16x16x32_bf16(w1r[1][kk], xf[kk], hacc[1], 0, 0, 0);
    }
    #pragma unroll
    for (int mt2 = 0; mt2 < 2; ++mt2) {
      float h0 = fmaxf(hacc[mt2][0], 0.f), h1 = fmaxf(hacc[mt2][1], 0.f);
      float h2 = fmaxf(hacc[mt2][2], 0.f), h3 = fmaxf(hacc[mt2][3], 0.f);
      uint2 p; p.x = pkbf(h0, h1); p.y = pkbf(h2, h3);
      *(uint2*)&hs[lr * HSTR + mt2 * 16 + q * 4] = p;
    }
    bf16x8 ah = *(const bf16x8*)&hs[lr * HSTR + q * 8];
    f32x4 cacc[8];
    #pragma unroll
    for (int mt = 0; mt < 8; ++mt) {
      cacc[mt][0] = b2v[mt].x; cacc[mt][1] = b2v[mt].y;
      cacc[mt][2] = b2v[mt].z; cacc[mt][3] = b2v[mt].w;
    }
    #pragma unroll
    for (int mt = 0; mt < 8; ++mt)
      cacc[mt] = __builtin_amdgcn_mfma_f32_16x16x32_bf16(w2r[mt], ah, cacc[mt], 0, 0, 0);
    #pragma unroll
    for (int mt = 0; mt < 8; ++mt) {
      float4 xg = *(const float4*)&lds[lr * 128 + ((mt * 4 + q) ^ swz) * 4];
      y[mt][0] = xg.x * (1.f + tanh_fast(cacc[mt][0]));
      y[mt][1] = xg.y * (1.f + tanh_fast(cacc[mt][1]));
      y[mt][2] = xg.z * (1.f + tanh_fast(cacc[mt][2]));
      y[mt][3] = xg.w * (1.f + tanh_fast(cacc[mt][3]));
    }
  };

  // ================= PASS 1: mean accumulate =================
  float macc[8][4];
  #pragma unroll
  for (int mt = 0; mt < 8; ++mt)
    #pragma unroll
    for (int c = 0; c < 4; ++c) macc[mt][c] = 0.f;

  {
    int ti = w, cur = 0;
    if (ti < ntile) fill(cur, ti * 16);
    for (; ti < ntile; ti += 4) {
      const int tn = ti + 4;
      if (tn < ntile) {
        fill(cur ^ 1, tn * 16);
        asm volatile("s_waitcnt vmcnt(8)" ::: "memory");
      } else {
        asm volatile("s_waitcnt vmcnt(0)" ::: "memory");
      }
      float y[8][4];
      mlp(cur, y);
      if (ti * 16 + lr < cnt) {
        #pragma unroll
        for (int mt = 0; mt < 8; ++mt)
          #pragma unroll
          for (int c = 0; c < 4; ++c) macc[mt][c] += y[mt][c];
      }
      cur ^= 1;
    }
  }
  __syncthreads();

  // ---- mean reduce: over lr lanes (xor 1,2,4,8), cross-wave via part ----
  #pragma unroll
  for (int mt = 0; mt < 8; ++mt)
    #pragma unroll
    for (int c = 0; c < 4; ++c) {
      float v = macc[mt][c];
      v += __shfl_xor(v, 1, 64);
      v += __shfl_xor(v, 2, 64);
      v += __shfl_xor(v, 4, 64);
      v += __shfl_xor(v, 8, 64);
      macc[mt][c] = v;
    }
  if (lr == 0) {
    #pragma unroll
    for (int mt = 0; mt < 8; ++mt)
      *(float4*)&part[w][mt * 16 + q * 4] =
          make_float4(macc[mt][0], macc[mt][1], macc[mt][2], macc[mt][3]);
  }
  __syncthreads();
  if (t < DDIM) {
    float m = part[0][t] + part[1][t] + part[2][t] + part[3][t];
    meanv[t] = m / (float)cnt;
  }
  __syncthreads();

  // ---- tg = tanh(mean @ W): 2 thr/col x 64 k, coalesced ----
  {
    const int c = t & 127, s = t >> 7;
    float a = 0.f;
    #pragma unroll 8
    for (int k = 0; k < 64; ++k)
      a = fmaf(meanv[s * 64 + k], W[(size_t)(s * 64 + k) * DDIM + c], a);
    part[s][c] = a;
  }
  __syncthreads();
  if (t < DDIM) tgs[t] = tanh_fast(part[0][t] + part[1][t]);
  __syncthreads();

  // ================= PASS 2: re-stream (L3-hot), coef, out =================
  float oacc[8][4];
  #pragma unroll
  for (int mt = 0; mt < 8; ++mt)
    #pragma unroll
    for (int c = 0; c < 4; ++c) oacc[mt][c] = 0.f;

  // tg fragments to registers once (keep loop VMEM/LDS-light)
  float tgv[8][4];
  #pragma unroll
  for (int mt = 0; mt < 8; ++mt) {
    float4 tv = *(const float4*)&tgs[mt * 16 + q * 4];
    tgv[mt][0] = tv.x; tgv[mt][1] = tv.y; tgv[mt][2] = tv.z; tgv[mt][3] = tv.w;
  }

  {
    int ti = w, cur = 0;
    if (ti < ntile) fill(cur, ti * 16);
    for (; ti < ntile; ti += 4) {
      const int tn = ti + 4;
      if (tn < ntile) {
        fill(cur ^ 1, tn * 16);
        asm volatile("s_waitcnt vmcnt(8)" ::: "memory");
      } else {
        asm volatile("s_waitcnt vmcnt(0)" ::: "memory");
      }
      float y[8][4];
      mlp(cur, y);
      float p = 0.f;
      #pragma unroll
      for (int mt = 0; mt < 8; ++mt) {
        p = fmaf(y[mt][0], tgv[mt][0], p); p = fmaf(y[mt][1], tgv[mt][1], p);
        p = fmaf(y[mt][2], tgv[mt][2], p); p = fmaf(y[mt][3], tgv[mt][3], p);
      }
      p += __shfl_xor(p, 16, 64);
      p += __shfl_xor(p, 32, 64);
      const float coef = sigmoid_fast(p);
      if (ti * 16 + lr < cnt) {
        #pragma unroll
        for (int mt = 0; mt < 8; ++mt)
          #pragma unroll
          for (int c = 0; c < 4; ++c)
            oacc[mt][c] = fmaf(coef, y[mt][c], oacc[mt][c]);
      }
      cur ^= 1;
    }
  }
  __syncthreads();

  // ---- out reduce ----
  #pragma unroll
  for (int mt = 0; mt < 8; ++mt)
    #pragma unroll
    for (int c = 0; c < 4; ++c) {
      float v = oacc[mt][c];
      v += __shfl_xor(v, 1, 64);
      v += __shfl_xor(v, 2, 64);
      v += __shfl_xor(v, 4, 64);
      v += __shfl_xor(v, 8, 64);
      oacc[mt][c] = v;
    }
  if (lr == 0) {
    #pragma unroll
    for (int mt = 0; mt < 8; ++mt)
      *(float4*)&part[w][mt * 16 + q * 4] =
          make_float4(oacc[mt][0], oacc[mt][1], oacc[mt][2], oacc[mt][3]);
  }
  __syncthreads();
  if (t < DDIM)
    out[(size_t)g * DDIM + t] = part[0][t] + part[1][t] + part[2][t] + part[3][t];
}

// ---------------------------------------------------------------------------
extern "C" void kernel_launch(void* const* d_in, const int* in_sizes, int n_in,
                              void* d_out, int out_size, void* d_ws, size_t ws_size,
                              hipStream_t stream) {
  const float* x     = (const float*)d_in[0];
  const int*   batch = (const int*)d_in[1];
  const float* w1 = (const float*)d_in[3];
  const float* b1 = (const float*)d_in[4];
  const float* w2 = (const float*)d_in[5];
  const float* b2 = (const float*)d_in[6];
  const float* W  = (const float*)d_in[7];
  float* out = (float*)d_out;

  const int N = in_sizes[0] / DDIM;
  const int G = out_size / DDIM;

  // ws: [w1tf 4096 u16][w2tf 4096 u16][bounds G+1 int]  (no x2!)
  unsigned short* w1tf = (unsigned short*)d_ws;
  unsigned short* w2tf = w1tf + 4096;
  int* bounds = (int*)(w2tf + 4096);
  (void)ws_size; (void)n_in;

  hipLaunchKernelGGL(k0_prep, dim3(4), dim3(PBLK), 0, stream, w1, w2, w1tf, w2tf);
  hipLaunchKernelGGL(kb_bounds, dim3((G + 1 + PBLK - 1) / PBLK), dim3(PBLK), 0, stream,
                     batch, bounds, N, G);
  hipLaunchKernelGGL(k_fused, dim3(G), dim3(BLK), 0, stream,
                     x, w1tf, b1, w2tf, b2, W, bounds, out, N);
}